// Round 9
// baseline (158.844 us; speedup 1.0000x reference)
//
#include <hip/hip_runtime.h>
#include <hip/hip_bf16.h>
#include <stdint.h>

typedef __attribute__((ext_vector_type(8))) short bf16x8;
typedef __attribute__((ext_vector_type(4))) short bf16x4;
typedef __attribute__((ext_vector_type(4))) float f32x4;
typedef __attribute__((ext_vector_type(4))) unsigned short us4;

#define MFMA32(a, b, c) __builtin_amdgcn_mfma_f32_16x16x32_bf16(a, b, c, 0, 0, 0)

#if defined(__has_builtin) && __has_builtin(__builtin_amdgcn_mfma_f32_16x16x16bf16_1k)
__device__ __forceinline__ f32x4 MFMA16(bf16x4 a, bf16x4 b, f32x4 c) {
    return __builtin_amdgcn_mfma_f32_16x16x16bf16_1k(a, b, c, 0, 0, 0);
}
#elif defined(__has_builtin) && __has_builtin(__builtin_amdgcn_mfma_f32_16x16x16_bf16)
__device__ __forceinline__ f32x4 MFMA16(bf16x4 a, bf16x4 b, f32x4 c) {
    return __builtin_amdgcn_mfma_f32_16x16x16_bf16(a, b, c, 0, 0, 0);
}
#else
__device__ __forceinline__ f32x4 MFMA16(bf16x4 a, bf16x4 b, f32x4 c) {
    f32x4 d;
    // early-clobber: D must not alias A/B registers
    asm volatile("v_mfma_f32_16x16x16_bf16 %0, %1, %2, %3\n\ts_nop 7\n\ts_nop 2"
                 : "=&v"(d) : "v"(a), "v"(b), "v"(c));
    return d;
}
#endif

__device__ __forceinline__ short f2bf(float f) {
    union { float f; uint32_t u; } v; v.f = f;
    uint32_t u = v.u;
    u = (u + 0x7FFFu + ((u >> 16) & 1u)) >> 16;  // RNE
    return (short)u;
}
__device__ __forceinline__ float bf2f(short s) {
    union { uint32_t u; float f; } v; v.u = ((uint32_t)(unsigned short)s) << 16;
    return v.f;
}
__device__ __forceinline__ uint32_t cvt_pk_bf16(float lo, float hi) {
    uint32_t r;
    asm("v_cvt_pk_bf16_f32 %0, %1, %2" : "=v"(r) : "v"(lo), "v"(hi));
    return r;
}

#define QSCALE 0.18033688011112042f   // 0.125 * log2(e)
#define CH 12        // KV tiles (of 64 keys) per wave-task
#define NTASK 408    // per batch: sum_u ceil(((u>>1)+1)/CH)
#define NCH(u) ((((u) >> 1) + CH) / CH)   // ceil((lt+1)/CH), lt = u>>1

// ---------------------------------------------------------------------------
// Kernel 1: WT_bf16[192][1024] (cols 0-63 Wq*QSCALE | 64-127 Wk | 128-191 Wv),
// biasC[192], task tables (heavy-first): TB=qtile, TC=chunk, OFF[u].
// ---------------------------------------------------------------------------
__global__ void wt_prep(const float* __restrict__ Wk, const float* __restrict__ bk,
                        const float* __restrict__ Wq, const float* __restrict__ bq,
                        const float* __restrict__ Wv, const float* __restrict__ bv,
                        short* __restrict__ WT, float* __restrict__ biasC,
                        unsigned char* __restrict__ TB, unsigned char* __restrict__ TC,
                        int* __restrict__ OFF) {
    int i = blockIdx.x * 256 + threadIdx.x;
    if (i < 192 * 1024) {
        int c = i >> 10, k = i & 1023, cc = c & 63;
        const float* W; float sc;
        if (c < 64)       { W = Wq; sc = QSCALE; }
        else if (c < 128) { W = Wk; sc = 1.0f;   }
        else              { W = Wv; sc = 1.0f;   }
        WT[i] = f2bf(W[k * 64 + cc] * sc);
    }
    if (blockIdx.x == 0 && threadIdx.x < 192) {
        int c = threadIdx.x;
        float bb;
        if (c < 64)       bb = bq[c] * QSCALE;
        else if (c < 128) bb = bk[c - 64];
        else              bb = bv[c - 128];
        biasC[c] = bb;
    }
    if (blockIdx.x == 1 && threadIdx.x == 0) {
        int cum = 0;
        for (int u = 127; u >= 0; u--) {          // heavy qtiles first
            OFF[u] = cum;
            const int nch = NCH(u);
            for (int c = 0; c < nch; c++) {
                TB[cum] = (unsigned char)u;
                TC[cum] = (unsigned char)c;
                cum++;
            }
        }
    }
}

// ---------------------------------------------------------------------------
// Kernel 2: QKV projection — EXACT R4-validated version (LDS staging +
// 4-wave K-split + LDS merge). 1024 blocks x 256 thr; block = 16 rows.
// ---------------------------------------------------------------------------
__global__ __launch_bounds__(256) void qkv_proj(
        const float* __restrict__ X, const short* __restrict__ WT,
        const float* __restrict__ biasC,
        short* __restrict__ Qb, short* __restrict__ Kb, short* __restrict__ Vt) {
    union SM {
        short stage[16][1032];        // 33 KB, pad 8 -> conflict-free frags
        float merge[12][16][4][17];   // 52 KB
    };
    __shared__ SM sm;
    const int t = threadIdx.x;
    const int lane = t & 63, w = t >> 6, l15 = lane & 15, h = lane >> 4;
    const int row0 = blockIdx.x * 16;

    // ---- stage X tile (16 x 1024) as bf16; 512B-contiguous global reads ----
    {
        const int srow = t >> 4, sl = t & 15;
        const float* xr = X + (size_t)(row0 + srow) * 1024 + sl * 8;
        short* dr = &sm.stage[srow][sl * 8];
#pragma unroll
        for (int it = 0; it < 8; it++) {
            const float4 a0 = *(const float4*)(xr + it * 128);
            const float4 a1 = *(const float4*)(xr + it * 128 + 4);
            uint4 pk;
            pk.x = cvt_pk_bf16(a0.x, a0.y);
            pk.y = cvt_pk_bf16(a0.z, a0.w);
            pk.z = cvt_pk_bf16(a1.x, a1.y);
            pk.w = cvt_pk_bf16(a1.z, a1.w);
            *(uint4*)(dr + it * 128) = pk;
        }
    }
    __syncthreads();

    f32x4 acc[12];
#pragma unroll
    for (int ct = 0; ct < 12; ct++) acc[ct] = (f32x4){0.f, 0.f, 0.f, 0.f};

    const short* ar = &sm.stage[l15][w * 256 + h * 8];
    const short* wb = WT + (size_t)l15 * 1024 + w * 256 + h * 8;

    for (int kc = 0; kc < 256; kc += 32) {
        const bf16x8 af = *(const bf16x8*)(ar + kc);
#pragma unroll
        for (int ct = 0; ct < 12; ct++) {
            const bf16x8 bf = *(const bf16x8*)(wb + (size_t)ct * 16 * 1024 + kc);
            acc[ct] = MFMA32(af, bf, acc[ct]);
        }
    }
    __syncthreads();   // stage dead, reuse as merge buffer

#pragma unroll
    for (int ct = 0; ct < 12; ct++)
#pragma unroll
        for (int r = 0; r < 4; r++)
            sm.merge[ct][h * 4 + r][w][l15] = acc[ct][r];
    __syncthreads();

    const int b = row0 >> 12, srow = row0 & 4095;

    // Q (ct 0-3) and K (ct 4-7)
#pragma unroll
    for (int i = 0; i < 8; i++) {
        const int e = t + 256 * i;
        const int ct = e >> 8, row = (e >> 4) & 15, col = e & 15;
        float val = sm.merge[ct][row][0][col] + sm.merge[ct][row][1][col]
                  + sm.merge[ct][row][2][col] + sm.merge[ct][row][3][col]
                  + biasC[ct * 16 + col];
        if (ct < 4) Qb[(size_t)(row0 + row) * 64 + ct * 16 + col] = f2bf(val);
        else        Kb[(size_t)(row0 + row) * 64 + (ct - 4) * 16 + col] = f2bf(val);
    }
    // V -> Vt[b][hd][s] (transposed), packed 4-s stores
    {
        const int ctv = (t >> 4) & 3;
        const int col = t & 15;
        const int rg = t >> 6;
        const int hd = ctv * 16 + col;
        const float bias = biasC[128 + hd];
        us4 pk;
#pragma unroll
        for (int r = 0; r < 4; r++) {
            const int row = rg * 4 + r;
            float val = sm.merge[8 + ctv][row][0][col] + sm.merge[8 + ctv][row][1][col]
                      + sm.merge[8 + ctv][row][2][col] + sm.merge[8 + ctv][row][3][col] + bias;
            pk[r] = (unsigned short)f2bf(val);
        }
        *(us4*)(Vt + ((size_t)(b * 64 + hd)) * 4096 + srow + rg * 4) = pk;
    }
}

// ---------------------------------------------------------------------------
// Kernel 3: causal flash attention; each WAVE is an independent task
// (b, qtile u, CH-tile key chunk c). Inner per-tile body is the EXACT
// R4-validated ordering (K at loop top, V after softmax, no prefetch).
// ---------------------------------------------------------------------------
__device__ __forceinline__ void softmax_update(const f32x4 s[4], float& m, float& l,
                                               f32x4 o[4], bf16x4 pb[4]) {
    float mx = s[0][0];
#pragma unroll
    for (int c = 0; c < 4; c++)
#pragma unroll
        for (int r = 0; r < 4; r++) mx = fmaxf(mx, s[c][r]);
    mx = fmaxf(mx, __shfl_xor(mx, 16));
    mx = fmaxf(mx, __shfl_xor(mx, 32));
    const float mn = fmaxf(m, mx);
    const float fac = exp2f(m - mn);
    m = mn;
    float p[4][4];
    float sum = 0.f;
#pragma unroll
    for (int c = 0; c < 4; c++)
#pragma unroll
        for (int r = 0; r < 4; r++) { p[c][r] = exp2f(s[c][r] - mn); sum += p[c][r]; }
    sum += __shfl_xor(sum, 16);
    sum += __shfl_xor(sum, 32);
    l = l * fac + sum;
#pragma unroll
    for (int c = 0; c < 4; c++) o[c] *= fac;
#pragma unroll
    for (int c = 0; c < 4; c++) {
        union { bf16x4 v; uint32_t u[2]; } pk;
        pk.u[0] = cvt_pk_bf16(p[c][0], p[c][1]);
        pk.u[1] = cvt_pk_bf16(p[c][2], p[c][3]);
        pb[c] = pk.v;
    }
}

__global__ __launch_bounds__(256) void attn(
        const short* __restrict__ Qb, const short* __restrict__ Kb,
        const short* __restrict__ Vt, const unsigned char* __restrict__ TB,
        const unsigned char* __restrict__ TC,
        short* __restrict__ PO, float* __restrict__ PM, float* __restrict__ PL) {
    const int lane = threadIdx.x & 63, wg = threadIdx.x >> 6;
    const int l15 = lane & 15, h = lane >> 4;
    const int gid = blockIdx.x * 4 + wg;          // global wave-task id
    const int b = gid / NTASK, jj = gid - b * NTASK;
    const int u = TB[jj];
    const int c = TC[jj];
    const int row32 = u * 32;
    const int lt = u >> 1;                        // diagonal KV tile
    const int t0 = c * CH;
    const int t1 = min(t0 + CH - 1, lt);
    const size_t bbase = (size_t)b * 4096 * 64;

    const short* qp0 = Qb + bbase + (size_t)(row32 + l15) * 64 + h * 8;
    const short* qp1 = qp0 + 16 * 64;
    const bf16x8 q00 = *(const bf16x8*)qp0,  q01 = *(const bf16x8*)(qp0 + 32);
    const bf16x8 q10 = *(const bf16x8*)qp1,  q11 = *(const bf16x8*)(qp1 + 32);

    f32x4 o0[4], o1[4];
    float m0 = -__builtin_inff(), m1 = -__builtin_inff(), l0 = 0.f, l1 = 0.f;
#pragma unroll
    for (int t = 0; t < 4; t++) { o0[t] = (f32x4){0,0,0,0}; o1[t] = (f32x4){0,0,0,0}; }

    for (int kt = t0; kt <= t1; ++kt) {
        const short* kb = Kb + bbase + (size_t)kt * 4096;
        f32x4 s0[4], s1[4];
#pragma unroll
        for (int cc = 0; cc < 4; cc++) {
            const short* kp = kb + (size_t)(cc * 16 + l15) * 64 + h * 8;
            const bf16x8 kf0 = *(const bf16x8*)kp;
            const bf16x8 kf1 = *(const bf16x8*)(kp + 32);
            f32x4 z = (f32x4){0,0,0,0};
            z = MFMA32(kf0, q00, z);  s0[cc] = MFMA32(kf1, q01, z);
            z = (f32x4){0,0,0,0};
            z = MFMA32(kf0, q10, z);  s1[cc] = MFMA32(kf1, q11, z);
        }
        if (kt == lt) {   // diagonal: mask key > q
            const int q0g = row32 + l15, q1g = q0g + 16;
#pragma unroll
            for (int cc = 0; cc < 4; cc++) {
#pragma unroll
                for (int r = 0; r < 4; r++) {
                    const int key = kt * 64 + cc * 16 + h * 4 + r;
                    if (key > q0g) s0[cc][r] = -1e30f;
                    if (key > q1g) s1[cc][r] = -1e30f;
                }
            }
        }
        bf16x4 pb0[4], pb1[4];
        softmax_update(s0, m0, l0, o0, pb0);
        softmax_update(s1, m1, l1, o1, pb1);

        const short* vb = Vt + (size_t)b * 64 * 4096 + kt * 64;
#pragma unroll
        for (int ct = 0; ct < 4; ct++) {
            const short* vp = vb + (size_t)(ct * 16 + l15) * 4096 + h * 4;
#pragma unroll
            for (int cc = 0; cc < 4; cc++) {
                const bf16x4 vf = *(const bf16x4*)(vp + cc * 16);
                o0[ct] = MFMA16(vf, pb0[cc], o0[ct]);
                o1[ct] = MFMA16(vf, pb1[cc], o1[ct]);
            }
        }
    }

    // ---- write per-wave partial (m, l, O-bf16) ----
    if (h == 0) {
        PM[(size_t)gid * 32 + l15] = m0;  PM[(size_t)gid * 32 + 16 + l15] = m1;
        PL[(size_t)gid * 32 + l15] = l0;  PL[(size_t)gid * 32 + 16 + l15] = l1;
    }
    short* po = PO + (size_t)gid * 2048;
#pragma unroll
    for (int ct = 0; ct < 4; ct++) {
        uint2 w0, w1;
        w0.x = cvt_pk_bf16(o0[ct][0], o0[ct][1]);
        w0.y = cvt_pk_bf16(o0[ct][2], o0[ct][3]);
        w1.x = cvt_pk_bf16(o1[ct][0], o1[ct][1]);
        w1.y = cvt_pk_bf16(o1[ct][2], o1[ct][3]);
        *(uint2*)(po + (size_t)l15 * 64 + ct * 16 + h * 4) = w0;
        *(uint2*)(po + (size_t)(16 + l15) * 64 + ct * 16 + h * 4) = w1;
    }
}

// ---------------------------------------------------------------------------
// Kernel 4: merge <=6 chunk partials per (b, qtile) and write output.
// ---------------------------------------------------------------------------
__global__ __launch_bounds__(256) void attn_merge(
        const short* __restrict__ PO, const float* __restrict__ PM,
        const float* __restrict__ PL, const int* __restrict__ OFF,
        float* __restrict__ out) {
    const int bu = blockIdx.x;
    const int b = bu >> 7, u = bu & 127;
    const int nc = NCH(u);
    const int base = b * NTASK + OFF[u];
    const int e = threadIdx.x;
    const int q = e >> 3, d0 = (e & 7) * 8;

    float M = -__builtin_inff();
    for (int c = 0; c < nc; c++) M = fmaxf(M, PM[(size_t)(base + c) * 32 + q]);
    float L = 0.f;
    float acc[8];
#pragma unroll
    for (int i = 0; i < 8; i++) acc[i] = 0.f;
    for (int c = 0; c < nc; c++) {
        const size_t slot = base + c;
        const float ew = exp2f(PM[slot * 32 + q] - M);
        L += ew * PL[slot * 32 + q];
        const bf16x8 ov = *(const bf16x8*)(PO + slot * 2048 + q * 64 + d0);
#pragma unroll
        for (int i = 0; i < 8; i++) acc[i] += ew * bf2f(ov[i]);
    }
    const float inv = 1.0f / L;
    float4 w0, w1;
    w0.x = acc[0] * inv; w0.y = acc[1] * inv; w0.z = acc[2] * inv; w0.w = acc[3] * inv;
    w1.x = acc[4] * inv; w1.y = acc[5] * inv; w1.z = acc[6] * inv; w1.w = acc[7] * inv;
    float* dst = out + (size_t)b * 4096 * 64 + (size_t)(u * 32 + q) * 64 + d0;
    *(float4*)dst = w0;
    *(float4*)(dst + 4) = w1;
}

// ---------------------------------------------------------------------------
extern "C" void kernel_launch(void* const* d_in, const int* in_sizes, int n_in,
                              void* d_out, int out_size, void* d_ws, size_t ws_size,
                              hipStream_t stream) {
    const float* x  = (const float*)d_in[0];
    // d_in[1] = causal mask (structure known, not read)
    const float* Wk = (const float*)d_in[2];
    const float* bk = (const float*)d_in[3];
    const float* Wq = (const float*)d_in[4];
    const float* bq = (const float*)d_in[5];
    const float* Wv = (const float*)d_in[6];
    const float* bv = (const float*)d_in[7];
    float* out = (float*)d_out;

    char* ws = (char*)d_ws;
    short* WT    = (short*)(ws);                           // 384 KB
    float* biasC = (float*)(ws + 393216);                  // 768 B
    unsigned char* TB = (unsigned char*)(ws + 394240);     // 408 B
    unsigned char* TC = (unsigned char*)(ws + 395264);     // 408 B
    int* OFF     = (int*)(ws + 396288);                    // 512 B
    short* Qb    = (short*)(ws + (size_t)1 * (1 << 20));   // 2 MB (exp2-scaled)
    short* Kb    = (short*)(ws + (size_t)3 * (1 << 20));   // 2 MB
    short* Vt    = (short*)(ws + (size_t)5 * (1 << 20));   // 2 MB, [b][hd][s]
    short* PO    = (short*)(ws + (size_t)7 * (1 << 20));   // 1632*4KB = 6.7 MB
    float* PM    = (float*)(ws + 14024704);                // 209 KB
    float* PL    = (float*)(ws + 14233600);                // 209 KB -> ends 13.8 MB

    wt_prep<<<768, 256, 0, stream>>>(Wk, bk, Wq, bq, Wv, bv, WT, biasC, TB, TC, OFF);
    qkv_proj<<<1024, 256, 0, stream>>>(x, WT, biasC, Qb, Kb, Vt);
    attn<<<408, 256, 0, stream>>>(Qb, Kb, Vt, TB, TC, PO, PM, PL);
    attn_merge<<<512, 256, 0, stream>>>(PO, PM, PL, OFF, out);
}